// Round 16
// baseline (1446.327 us; speedup 1.0000x reference)
//
#include <hip/hip_runtime.h>
#include <math.h>

typedef unsigned short u16;
typedef unsigned int u32;
typedef short bf16x8 __attribute__((ext_vector_type(8)));
typedef float f32x4 __attribute__((ext_vector_type(4)));

#define PI_F 3.14159265358979323846f

__device__ __forceinline__ float bf2f(u16 u){ union{u32 i; float f;} v; v.i=((u32)u)<<16; return v.f; }
__device__ __forceinline__ u16 f2bf(float f){ union{u32 i; float f;} v; v.f=f; u32 r=v.i+0x7fffu+((v.i>>16)&1u); return (u16)(r>>16); }
__device__ __forceinline__ float sigf(float x){ return 1.0f/(1.0f+expf(-x)); }

// ---------------- pack conv2 weights to bf16 fragment order: wpack[tap][chunk][oc][k=q*8+j] ----------------
__global__ __launch_bounds__(256) void wpack_kernel(const float* __restrict__ w2, u16* __restrict__ wpack)
{
  int e = blockIdx.x*256 + threadIdx.x;   // 36864 = 9*2*64*32
  if (e >= 36864) return;
  int k  = e & 31;
  int oc = (e>>5) & 63;
  int tc = e>>11;            // 0..17
  int tap = tc>>1, c = tc&1;
  int ic = c*32 + k;
  wpack[e] = f2bf(w2[(size_t)(oc*64 + ic)*9 + tap]);
}

// ---------------- pack wih (512x4096 f32) -> bf16 row-major ----------------
__global__ __launch_bounds__(256) void wihpack_kernel(const float* __restrict__ wih, u16* __restrict__ wihb)
{
  int e = blockIdx.x*256 + threadIdx.x;   // 2097152 total
  wihb[e] = f2bf(wih[e]);
}

// ---------------- conv1: img (B,2,64,64)[ch] f32 -> bf16 NHWC (B,64,64,64ch) (bias dropped: cancels in BN) ----------------
__global__ __launch_bounds__(256) void conv1_nhwc_kernel(
    const float* __restrict__ imgp, int ch,
    const float* __restrict__ w1, u16* __restrict__ out)
{
  int b = blockIdx.y, tile = blockIdx.x;
  int ty0 = (tile>>2)<<4, tx0 = (tile&3)<<4;
  int tid = threadIdx.x;
  __shared__ float patch[18*18];
  __shared__ float wsm[576];
  const float* ib = imgp + (((size_t)b*2 + ch)<<12);
  for (int e=tid; e<324; e+=256){
    int py = e/18, px = e - py*18;
    int gy = ty0+py-1, gx = tx0+px-1;
    float v = 0.f;
    if (gy>=0 && gy<64 && gx>=0 && gx<64) v = ib[(gy<<6)+gx];
    patch[e] = v;
  }
  for (int e=tid; e<576; e+=256) wsm[e] = w1[e];
  __syncthreads();
  int ty = tid>>4, tx = tid&15;
  float p[9];
  #pragma unroll
  for (int ky=0;ky<3;ky++)
    #pragma unroll
    for (int kx=0;kx<3;kx++) p[ky*3+kx] = patch[(ty+ky)*18 + tx+kx];
  u16* ob = out + ((((size_t)b<<12) + ((size_t)(ty0+ty)<<6) + (size_t)(tx0+tx))<<6);
  #pragma unroll
  for (int ocq=0; ocq<8; ocq++){
    u32 w4[4];
    #pragma unroll
    for (int pair=0; pair<4; pair++){
      float a0=0.f, a1=0.f;
      int oc0 = ocq*8 + pair*2;
      #pragma unroll
      for (int k=0;k<9;k++){ a0 += wsm[oc0*9+k]*p[k]; a1 += wsm[(oc0+1)*9+k]*p[k]; }
      w4[pair] = (u32)f2bf(a0) | ((u32)f2bf(a1)<<16);
    }
    ((uint4*)ob)[ocq] = make_uint4(w4[0],w4[1],w4[2],w4[3]);
  }
}

// ---------------- per-channel sum/sumsq over NHWC bf16 buf -> st[0..63]=sum, st[64..127]=sumsq ----------------
__device__ __forceinline__ void stats_body(const u16* __restrict__ buf, float* __restrict__ st, int blk, int tid)
{
  int c8 = (tid&7)*8;
  int pg = tid>>3;                 // 0..31
  size_t p0 = (size_t)blk*1024 + pg;
  float s[8], s2[8];
  #pragma unroll
  for (int k=0;k<8;k++){ s[k]=0.f; s2[k]=0.f; }
  for (int it=0; it<32; it++){
    size_t p = p0 + (size_t)it*32;
    uint4 v = *(const uint4*)(buf + (p<<6) + c8);
    u32 rw[4] = {v.x,v.y,v.z,v.w};
    #pragma unroll
    for (int d=0; d<4; d++){
      float f0 = bf2f((u16)(rw[d]&0xffff));
      float f1 = bf2f((u16)(rw[d]>>16));
      s[d*2]   += f0; s2[d*2]   += f0*f0;
      s[d*2+1] += f1; s2[d*2+1] += f1*f1;
    }
  }
  #pragma unroll
  for (int off=32; off>=8; off>>=1){
    #pragma unroll
    for (int k=0;k<8;k++){ s[k] += __shfl_down(s[k], off, 64); s2[k] += __shfl_down(s2[k], off, 64); }
  }
  __shared__ float sm[128];
  if (tid<128) sm[tid]=0.f;
  __syncthreads();
  if ((tid&63) < 8){
    int cb = tid&7;
    #pragma unroll
    for (int k=0;k<8;k++){
      atomicAdd(&sm[cb*8+k], s[k]);
      atomicAdd(&sm[64+cb*8+k], s2[k]);
    }
  }
  __syncthreads();
  if (tid<128) atomicAdd(&st[tid], sm[tid]);
}

__global__ __launch_bounds__(256) void stats_nhwc_kernel(const u16* __restrict__ buf, float* __restrict__ st)
{
  stats_body(buf, st, blockIdx.x, threadIdx.x);
}

__global__ __launch_bounds__(256) void stats_pair_kernel(
    const u16* __restrict__ A, const u16* __restrict__ B,
    float* __restrict__ stA, float* __restrict__ stB)
{
  const u16* buf = (blockIdx.x < 512)? A : B;
  float* st = (blockIdx.x < 512)? stA : stB;
  stats_body(buf, st, blockIdx.x & 511, threadIdx.x);
}

// ---------------- conv2 MFMA (R11-proven, 104 µs): 8-row x 16-col tiles, fused BN1+ReLU staging ----------------
__global__ __launch_bounds__(256) void conv2_mfma_kernel(
    const u16* __restrict__ in, const u16* __restrict__ wpack, u16* __restrict__ out,
    const float* __restrict__ st, const float* __restrict__ gam, const float* __restrict__ bet)
{
  int b = blockIdx.y, tile = blockIdx.x;     // 32 tiles: 8 y-tiles x 4 x-tiles
  int y0 = (tile>>2)*8, x0 = (tile&3)*16;
  int tid = threadIdx.x;
  int w = tid>>6, lane = tid&63;
  int m = lane&15, q = lane>>4;

  __shared__ __align__(16) u16 patch[11520];  // [py10][cq8][px18][j8]
  __shared__ float scs[64], shs[64];

  if (tid < 64){
    const float invN = 1.0f/524288.0f;
    float mean = st[tid]*invN;
    float var  = st[64+tid]*invN - mean*mean;
    float sc = gam[tid]*rsqrtf(var+1e-5f);
    scs[tid] = sc;
    shs[tid] = bet[tid] - mean*sc;
  }
  __syncthreads();

  for (int e=tid; e<1440; e+=256){
    int py = e/144; int rem = e - py*144;
    int px = rem>>3, cq = rem&7;
    int y = y0-1+py, x = x0-1+px;
    uint4 v = make_uint4(0,0,0,0);
    if (y>=0 && y<64 && x>=0 && x<64){
      uint4 raw = *(const uint4*)(in + ((((size_t)b<<12) + ((size_t)y<<6) + (size_t)x)<<6) + cq*8);
      u32 rw[4] = {raw.x, raw.y, raw.z, raw.w};
      u32 ow[4];
      #pragma unroll
      for (int d=0; d<4; d++){
        u32 o = 0;
        #pragma unroll
        for (int h=0; h<2; h++){
          int c = cq*8 + d*2 + h;
          float f = bf2f((u16)((rw[d]>>(16*h))&0xffff))*scs[c] + shs[c];
          f = fmaxf(f, 0.f);
          o |= ((u32)f2bf(f)) << (16*h);
        }
        ow[d] = o;
      }
      v = make_uint4(ow[0],ow[1],ow[2],ow[3]);
    }
    *(uint4*)(patch + ((((py<<3)+cq)*18 + px)<<3)) = v;
  }
  __syncthreads();

  f32x4 acc[2][4];
  #pragma unroll
  for (int mt=0;mt<2;mt++)
    #pragma unroll
    for (int nt=0;nt<4;nt++) acc[mt][nt] = (f32x4){0.f,0.f,0.f,0.f};

  #pragma unroll
  for (int tap=0; tap<9; tap++){
    const int dy = tap/3, dx = tap%3;
    #pragma unroll
    for (int c=0; c<2; c++){
      const int kk = tap*2 + c;
      bf16x8 bw[4];
      #pragma unroll
      for (int nt=0; nt<4; nt++)
        bw[nt] = *(const bf16x8*)(wpack + (size_t)(kk*64 + nt*16 + m)*32 + q*8);
      #pragma unroll
      for (int mt=0; mt<2; mt++){
        int py = 2*w + mt + dy;
        bf16x8 av = *(const bf16x8*)(patch + ((((py<<3) + (c<<2) + q)*18 + (m+dx))<<3));
        #pragma unroll
        for (int nt=0; nt<4; nt++)
          acc[mt][nt] = __builtin_amdgcn_mfma_f32_16x16x32_bf16(av, bw[nt], acc[mt][nt], 0,0,0);
      }
    }
  }
  __syncthreads();
  // epilogue: C/D mapping col(oc)=lane&15, row(x)=q*4+reg
  u16* etile = patch;                        // reuse: 128px x 64oc bf16 = 16KB
  #pragma unroll
  for (int mt=0; mt<2; mt++){
    int lp = (2*w+mt)*16 + q*4;
    #pragma unroll
    for (int nt=0; nt<4; nt++)
      #pragma unroll
      for (int r=0; r<4; r++)
        etile[(lp+r)*64 + nt*16 + m] = f2bf(acc[mt][nt][r]);
  }
  __syncthreads();
  int lp = tid>>1, half = tid&1;
  int y = y0 + (lp>>4), x = x0 + (lp&15);
  uint4* gdst = (uint4*)(out + ((((size_t)b<<12) + ((size_t)y<<6) + (size_t)x)<<6) + half*32);
  const uint4* lsrc = (const uint4*)(etile + lp*64 + half*32);
  gdst[0] = lsrc[0];
  gdst[1] = lsrc[1];
  gdst[2] = lsrc[2];
  gdst[3] = lsrc[3];
}

// ---------------- glimpser params -> global (final lstm only; dead sinks) ----------------
__device__ __forceinline__ void compute_params_lane(
    int b, int lane, float h0, float h1,
    const float* __restrict__ gw, const float* __restrict__ gb,
    float* __restrict__ FhT, float* __restrict__ Fw)
{
  float gpv[3];
  #pragma unroll
  for (int k=0;k<3;k++){
    float p = h0*gw[k*128+lane] + h1*gw[k*128+64+lane];
    #pragma unroll
    for (int off=32; off>0; off>>=1) p += __shfl_down(p, off, 64);
    float tot = __shfl(p, 0, 64);
    gpv[k] = tanhf(tot + gb[k]);
  }
  float ad = fabsf(gpv[2]);
  float delta = 8.0f*(1.0f-ad);
  float gamma = expf(1.0f-2.0f*ad);
  float inv_pg = 1.0f/(PI_F*gamma);
  float fi = (float)lane;
  float ctr = 31.5f*(gpv[0]+1.0f);
  float fh[8];
  #pragma unroll
  for (int g=0; g<8; g++){
    float mu = ctr + delta*((float)g - 3.5f);
    float u = (fi - mu)/gamma;
    float f = inv_pg/(1.0f+u*u);
    float s = f;
    #pragma unroll
    for (int off=32; off>0; off>>=1) s += __shfl_down(s, off, 64);
    s = __shfl(s, 0, 64);
    fh[g] = f/(s + 1e-4f);
  }
  float4* o = (float4*)(FhT + (((size_t)b<<6) + lane)*8);
  o[0] = make_float4(fh[0],fh[1],fh[2],fh[3]);
  o[1] = make_float4(fh[4],fh[5],fh[6],fh[7]);
  ctr = 31.5f*(gpv[1]+1.0f);
  #pragma unroll
  for (int wv=0; wv<8; wv++){
    float mu = ctr + delta*((float)wv - 3.5f);
    float u = (fi - mu)/gamma;
    float f = inv_pg/(1.0f+u*u);
    float s = f;
    #pragma unroll
    for (int off=32; off>0; off>>=1) s += __shfl_down(s, off, 64);
    s = __shfl(s, 0, 64);
    Fw[(((size_t)b<<3)+wv)*64 + lane] = f/(s + 1e-4f);
  }
}

// ---------------- glimpser params -> LDS, 4-wave parallel (gpv redundant per wave; g/wv split 2-per-wave) ----------------
__device__ __forceinline__ void compute_params_lds_all(
    int tid, int jc, const float* __restrict__ hnew,
    const float* __restrict__ gw, const float* __restrict__ gb,
    float* __restrict__ fh_lds, float* __restrict__ fw_lds)
{
  int lane = tid & 63, w = tid >> 6;
  if (w >= 4) return;                    // waves 4..7 proceed to barrier
  float h0 = hnew[lane], h1 = hnew[64+lane];
  float gpv[3];
  #pragma unroll
  for (int k=0;k<3;k++){
    float p = h0*gw[k*128+lane] + h1*gw[k*128+64+lane];
    #pragma unroll
    for (int off=32; off>0; off>>=1) p += __shfl_down(p, off, 64);
    float tot = __shfl(p, 0, 64);
    gpv[k] = tanhf(tot + gb[k]);
  }
  float ad = fabsf(gpv[2]);
  float delta = 8.0f*(1.0f-ad);
  float gamma = expf(1.0f-2.0f*ad);
  float inv_pg = 1.0f/(PI_F*gamma);
  float fi = (float)lane;
  float ctrH = 31.5f*(gpv[0]+1.0f);
  #pragma unroll
  for (int gg=0; gg<2; gg++){
    int g = w*2 + gg;
    float mu = ctrH + delta*((float)g - 3.5f);
    float u = (fi - mu)/gamma;
    float f = inv_pg/(1.0f+u*u);
    float s = f;
    #pragma unroll
    for (int off=32; off>0; off>>=1) s += __shfl_down(s, off, 64);
    s = __shfl(s, 0, 64);
    fh_lds[lane*8+g] = f/(s + 1e-4f);      // [i=lane][g]
  }
  float ctrW = 31.5f*(gpv[1]+1.0f);
  #pragma unroll
  for (int gg=0; gg<2; gg++){
    int wv = w*2 + gg;
    float mu = ctrW + delta*((float)wv - 3.5f);
    float u = (fi - mu)/gamma;
    float f = inv_pg/(1.0f+u*u);
    float s = f;
    #pragma unroll
    for (int off=32; off>0; off>>=1) s += __shfl_down(s, off, 64);
    s = __shfl(s, 0, 64);
    int jl = lane - jc*16;
    if (jl >= 0 && jl < 16) fw_lds[jl*8+wv] = f/(s + 1e-4f);   // [jl][w]
  }
}

// ---------------- glimpse + folded LSTM/params: 512 threads, dual-buffer row combine ----------------
// img holds RAW conv2 output; per element: v = max(x*sc2 + sh2 + res, 0) before the Fh contraction.
// Rows 0-31 accumulate into t_lds0 (ih0 write, ih1 add); rows 32-63 into t_lds1 (ih2 write, ih3 add).
// 2 barriers instead of 4; phase 2 reads buf0+buf1.
__global__ __launch_bounds__(512,4) void glimpse_lstm_kernel(
    const u16* __restrict__ img, const float* __restrict__ part,
    const float* __restrict__ whhT,
    const float* __restrict__ bih, const float* __restrict__ bhh,
    const float* __restrict__ gw, const float* __restrict__ gb,
    const float* __restrict__ Hx_in, const float* __restrict__ Cx_in,
    float* __restrict__ Hx_out, float* __restrict__ Cx_out,
    float* __restrict__ part_gl,
    const float* __restrict__ st2, const float* __restrict__ gam2,
    const float* __restrict__ bet2, const float* __restrict__ imgp,
    int ch, int t)
{
  int jc = blockIdx.x, b = blockIdx.y;
  int tid = threadIdx.x;
  __shared__ float hs[128];
  __shared__ float hnew[128];
  __shared__ float gsm[512];
  __shared__ float scs[64], shs[64];
  __shared__ __align__(16) float fh_lds[512];      // [i][g]
  __shared__ __align__(16) float fw_lds[128];      // [jl][w]
  __shared__ __align__(16) float t_lds0[8*16*64];  // [g][j][c] rows 0-31
  __shared__ __align__(16) float t_lds1[8*16*64];  // [g][j][c] rows 32-63

  // ---- BN2 coefficients ----
  if (tid < 64){
    const float invN = 1.0f/524288.0f;
    float mean = st2[tid]*invN;
    float var  = st2[64+tid]*invN - mean*mean;
    float sc = gam2[tid]*rsqrtf(var+1e-5f);
    scs[tid] = sc;
    shs[tid] = bet2[tid] - mean*sc;
  }

  // ---- folded LSTM (512 threads: n = tid covers all 512 gates directly) ----
  if (t > 0){
    if (tid < 128) hs[tid] = Hx_in[b*128+tid];
    __syncthreads();
    {
      int n = tid;
      float acc = bih[n] + bhh[n];
      const float* pp = part + (size_t)b*16384 + n;
      #pragma unroll 8
      for (int ks=0; ks<32; ks++) acc += pp[ks*512];
      const float* wp = whhT + n;
      #pragma unroll 8
      for (int k=0;k<128;k++) acc += hs[k]*wp[(size_t)k*512];
      gsm[n] = acc;
    }
    __syncthreads();
    if (tid < 128){
      float cx = Cx_in[b*128+tid];
      float cn = sigf(gsm[128+tid])*cx + sigf(gsm[tid])*tanhf(gsm[256+tid]);
      float hn = sigf(gsm[384+tid])*tanhf(cn);
      hnew[tid] = hn;
      if (jc == 0){ Cx_out[b*128+tid] = cn; Hx_out[b*128+tid] = hn; }
    }
  } else {
    if (tid < 128) hnew[tid] = 0.f;
  }
  __syncthreads();

  // ---- params in-LDS (4 waves in parallel) ----
  compute_params_lds_all(tid, jc, hnew, gw, gb, fh_lds, fw_lds);
  __syncthreads();

  // ---- glimpse phase 1: uint4 loads + BN2/res/relu, 4-way row split (16 rows each) ----
  int ih = tid>>7, j = (tid>>3)&15, cg = tid&7;
  float scq[8], shq[8];
  #pragma unroll
  for (int k=0;k<8;k++){ scq[k] = scs[cg*8+k]; shq[k] = shs[cg*8+k]; }
  f32x4 accA[8], accB[8];
  #pragma unroll
  for (int g=0;g<8;g++){ accA[g]=(f32x4){0.f,0.f,0.f,0.f}; accB[g]=(f32x4){0.f,0.f,0.f,0.f}; }
  const u16* ib = img + ((((size_t)b<<12) + ((size_t)(ih*16)<<6) + (size_t)(jc*16+j))<<6) + cg*8;
  const float* rp = imgp + (((size_t)(b*2+ch))<<12) + ((size_t)(ih*16)<<6) + (jc*16+j);
  #pragma unroll 8
  for (int ii=0; ii<16; ii++){
    uint4 vv = *(const uint4*)(ib + ((size_t)ii<<12));
    float res = rp[ii<<6];
    float x0=fmaxf(bf2f((u16)(vv.x&0xffff))*scq[0]+shq[0]+res, 0.f);
    float x1=fmaxf(bf2f((u16)(vv.x>>16))   *scq[1]+shq[1]+res, 0.f);
    float x2=fmaxf(bf2f((u16)(vv.y&0xffff))*scq[2]+shq[2]+res, 0.f);
    float x3=fmaxf(bf2f((u16)(vv.y>>16))   *scq[3]+shq[3]+res, 0.f);
    float x4=fmaxf(bf2f((u16)(vv.z&0xffff))*scq[4]+shq[4]+res, 0.f);
    float x5=fmaxf(bf2f((u16)(vv.z>>16))   *scq[5]+shq[5]+res, 0.f);
    float x6=fmaxf(bf2f((u16)(vv.w&0xffff))*scq[6]+shq[6]+res, 0.f);
    float x7=fmaxf(bf2f((u16)(vv.w>>16))   *scq[7]+shq[7]+res, 0.f);
    int i = ih*16+ii;
    f32x4 fa = *(const f32x4*)&fh_lds[i*8];
    f32x4 fb = *(const f32x4*)&fh_lds[i*8+4];
    #pragma unroll
    for (int g=0;g<4;g++){
      accA[g][0]+=fa[g]*x0; accA[g][1]+=fa[g]*x1; accA[g][2]+=fa[g]*x2; accA[g][3]+=fa[g]*x3;
      accB[g][0]+=fa[g]*x4; accB[g][1]+=fa[g]*x5; accB[g][2]+=fa[g]*x6; accB[g][3]+=fa[g]*x7;
      accA[g+4][0]+=fb[g]*x0; accA[g+4][1]+=fb[g]*x1; accA[g+4][2]+=fb[g]*x2; accA[g+4][3]+=fb[g]*x3;
      accB[g+4][0]+=fb[g]*x4; accB[g+4][1]+=fb[g]*x5; accB[g+4][2]+=fb[g]*x6; accB[g+4][3]+=fb[g]*x7;
    }
  }
  // dual-buffer combine: ih0/ih2 write in parallel; barrier; ih1/ih3 add in parallel; barrier
  if (ih==0){
    #pragma unroll
    for (int g=0;g<8;g++){
      *(f32x4*)&t_lds0[(g*16+j)*64 + cg*8]     = accA[g];
      *(f32x4*)&t_lds0[(g*16+j)*64 + cg*8 + 4] = accB[g];
    }
  }
  if (ih==2){
    #pragma unroll
    for (int g=0;g<8;g++){
      *(f32x4*)&t_lds1[(g*16+j)*64 + cg*8]     = accA[g];
      *(f32x4*)&t_lds1[(g*16+j)*64 + cg*8 + 4] = accB[g];
    }
  }
  __syncthreads();
  if (ih==1){
    #pragma unroll
    for (int g=0;g<8;g++){
      f32x4* p0 = (f32x4*)&t_lds0[(g*16+j)*64 + cg*8];
      p0[0] = p0[0] + accA[g];
      p0[1] = p0[1] + accB[g];
    }
  }
  if (ih==3){
    #pragma unroll
    for (int g=0;g<8;g++){
      f32x4* p0 = (f32x4*)&t_lds1[(g*16+j)*64 + cg*8];
      p0[0] = p0[0] + accA[g];
      p0[1] = p0[1] + accB[g];
    }
  }
  __syncthreads();

  // ---- glimpse phase 2: j-contraction (512 threads: 8 g-groups x 64 c) ----
  {
    int c = tid&63, s = tid>>6;        // s = g (0..7)
    float acc2[8];
    #pragma unroll
    for (int wv=0;wv<8;wv++) acc2[wv]=0.f;
    #pragma unroll
    for (int jl=0; jl<16; jl++){
      int idx = (((s<<4)+jl)<<6) + c;
      float tv = t_lds0[idx] + t_lds1[idx];
      f32x4 w0 = *(const f32x4*)&fw_lds[jl*8];
      f32x4 w1 = *(const f32x4*)&fw_lds[jl*8+4];
      acc2[0]+=tv*w0[0]; acc2[1]+=tv*w0[1]; acc2[2]+=tv*w0[2]; acc2[3]+=tv*w0[3];
      acc2[4]+=tv*w1[0]; acc2[5]+=tv*w1[1]; acc2[6]+=tv*w1[2]; acc2[7]+=tv*w1[3];
    }
    float* dst = part_gl + (((size_t)(b*4+jc))<<12) + c*64 + s*8;
    *(f32x4*)(dst+0) = (f32x4){acc2[0],acc2[1],acc2[2],acc2[3]};
    *(f32x4*)(dst+4) = (f32x4){acc2[4],acc2[5],acc2[6],acc2[7]};
  }
}

// ---------------- gates GEMM v3 (R14-proven): MFMA bf16. grid (4 n-tiles x 32 kb), 256 thr ----------------
__global__ __launch_bounds__(256) void gemm_ih_kernel(
    const float* __restrict__ part_gl, const u16* __restrict__ wihb, float* __restrict__ part)
{
  int n0 = blockIdx.x*128;
  int kb = blockIdx.y;
  int k0 = kb*128;
  __shared__ __align__(16) u16 AsmB[128*32];   // [m][k] bf16, 8 KB
  __shared__ __align__(16) u16 BsmB[128*32];   // [n][k] bf16, 8 KB
  int tid = threadIdx.x;
  int w = tid>>6, lane = tid&63;
  int m = lane&15, q = lane>>4;

  f32x4 acc[2][8];
  #pragma unroll
  for (int mf=0;mf<2;mf++)
    #pragma unroll
    for (int nf=0;nf<8;nf++) acc[mf][nf] = (f32x4){0.f,0.f,0.f,0.f};

  for (int ks=0; ks<4; ks++){
    int kbase = k0 + ks*32;
    // stage A: thread t -> row (t&127), k-half (t>>7)*16
    {
      int mr = tid & 127, half = tid >> 7;
      const float* pg = part_gl + ((size_t)mr<<14) + kbase + half*16;
      u16 tmpv[16];
      #pragma unroll
      for (int kq=0; kq<4; kq++){
        float4 a0 = *(const float4*)(pg + kq*4);
        float4 a1 = *(const float4*)(pg + 4096 + kq*4);
        float4 a2 = *(const float4*)(pg + 8192 + kq*4);
        float4 a3 = *(const float4*)(pg + 12288 + kq*4);
        tmpv[kq*4+0] = f2bf(a0.x+a1.x+a2.x+a3.x);
        tmpv[kq*4+1] = f2bf(a0.y+a1.y+a2.y+a3.y);
        tmpv[kq*4+2] = f2bf(a0.z+a1.z+a2.z+a3.z);
        tmpv[kq*4+3] = f2bf(a0.w+a1.w+a2.w+a3.w);
      }
      *(uint4*)(AsmB + mr*32 + half*16)     = *(uint4*)&tmpv[0];
      *(uint4*)(AsmB + mr*32 + half*16 + 8) = *(uint4*)&tmpv[8];
    }
    // stage B: thread t -> row n (t&127), k-half (t>>7)*16
    {
      int n = tid & 127, half = tid >> 7;
      const u16* wp = wihb + (size_t)(n0+n)*4096 + kbase + half*16;
      uint4 b0 = *(const uint4*)wp;
      uint4 b1 = *(const uint4*)(wp+8);
      *(uint4*)(BsmB + n*32 + half*16)     = b0;
      *(uint4*)(BsmB + n*32 + half*16 + 8) = b1;
    }
    __syncthreads();
    #pragma unroll
    for (int mf=0; mf<2; mf++){
      bf16x8 av = *(const bf16x8*)(AsmB + ((w*2+mf)*16 + m)*32 + q*8);
      #pragma unroll
      for (int nf=0; nf<8; nf++){
        bf16x8 bw = *(const bf16x8*)(BsmB + (nf*16 + m)*32 + q*8);
        acc[mf][nf] = __builtin_amdgcn_mfma_f32_16x16x32_bf16(av, bw, acc[mf][nf], 0,0,0);
      }
    }
    __syncthreads();
  }
  // store: row M = (w*2+mf)*16 + q*4 + r (= batch b), col N = nf*16 + m
  #pragma unroll
  for (int mf=0; mf<2; mf++){
    #pragma unroll
    for (int r=0; r<4; r++){
      int mrow = (w*2+mf)*16 + q*4 + r;
      float* pp = part + (size_t)mrow*16384 + kb*512 + n0;
      #pragma unroll
      for (int nf=0; nf<8; nf++)
        pp[nf*16 + m] = acc[mf][nf][r];
    }
  }
}

// ---------------- final LSTM update (produces H(16)); part layout [b][ks][n] ----------------
__global__ __launch_bounds__(256) void lstm_update_kernel(
    float* __restrict__ Hx, float* __restrict__ Cx,
    const float* __restrict__ part, const float* __restrict__ whhT,
    const float* __restrict__ b_ih, const float* __restrict__ b_hh,
    const float* __restrict__ gw, const float* __restrict__ gb,
    float* __restrict__ FhT, float* __restrict__ Fw)
{
  int b = blockIdx.x;
  int tid = threadIdx.x;
  int hid = tid & 127, half = tid >> 7;
  __shared__ float hs[128];
  __shared__ float hs2[128];
  __shared__ float gp[1024];     // [half][qd][hid]
  if (tid < 128) hs[tid] = Hx[b*128+tid];
  __syncthreads();
  #pragma unroll
  for (int qd=0; qd<4; qd++){
    int n = qd*128 + hid;
    float acc = half ? 0.f : (b_ih[n] + b_hh[n]);
    const float* pp = part + (size_t)b*16384 + (size_t)(half*16)*512 + n;
    #pragma unroll
    for (int ks=0; ks<16; ks++) acc += pp[ks*512];
    const float* wp = whhT + n + (size_t)(half*64)*512;
    const float* hp = hs + half*64;
    #pragma unroll 8
    for (int k=0;k<64;k++) acc += hp[k]*wp[(size_t)k*512];
    gp[(half*4+qd)*128 + hid] = acc;
  }
  __syncthreads();
  if (tid < 128){
    float g0 = gp[  0+tid] + gp[512+  0+tid];
    float g1 = gp[128+tid] + gp[512+128+tid];
    float g2 = gp[256+tid] + gp[512+256+tid];
    float g3 = gp[384+tid] + gp[512+384+tid];
    float cx = Cx[b*128+tid];
    float cn = sigf(g1)*cx + sigf(g0)*tanhf(g2);
    float hn = sigf(g3)*tanhf(cn);
    Cx[b*128+tid] = cn;
    Hx[b*128+tid] = hn;
    hs2[tid] = hn;
  }
  __syncthreads();
  if (tid < 64)
    compute_params_lane(b, tid, hs2[tid], hs2[64+tid], gw, gb, FhT, Fw);
}

__global__ __launch_bounds__(256) void transpose_whh_kernel(
    const float* __restrict__ whh, float* __restrict__ whhT)
{
  int idx = blockIdx.x*256 + threadIdx.x; // 65536 total
  int k = idx>>9, n = idx&511;
  whhT[idx] = whh[n*128 + k];
}

extern "C" void kernel_launch(void* const* d_in, const int* in_sizes, int n_in,
                              void* d_out, int out_size, void* d_ws, size_t ws_size,
                              hipStream_t stream)
{
  const float* imgp = (const float*)d_in[0];
  const float* w1  = (const float*)d_in[1];
  // d_in[2] = conv1 bias: cancels through bn1 -> unused
  const float* g1  = (const float*)d_in[3];
  const float* be1 = (const float*)d_in[4];
  const float* w2  = (const float*)d_in[5];
  // d_in[6] = conv2 bias: cancels through bn2 -> unused
  const float* g2  = (const float*)d_in[7];
  const float* be2 = (const float*)d_in[8];
  const float* wih = (const float*)d_in[9];
  const float* whh = (const float*)d_in[10];
  const float* bih = (const float*)d_in[11];
  const float* bhh = (const float*)d_in[12];
  const float* gw  = (const float*)d_in[13];
  const float* gb  = (const float*)d_in[14];

  char* ws = (char*)d_ws;
  u16* imgT    = (u16*)(ws + 0);           // RAW conv2 out (test), NHWC bf16
  u16* imgS    = (u16*)(ws + 67108864);    // RAW conv2 out (support)
  u16* tmp     = (u16*)(ws + 134217728);   // conv1 raw output, NHWC bf16 [134217728, 201326592)
  // turn-loop scratch overlays tmp (live only after conv phase):
  float* Hbuf1   = (float*)(ws + 134217728); // ping-pong H (65536)
  float* cbuf1   = (float*)(ws + 134283264); // ping-pong C (65536)
  float* part_gl = (float*)(ws + 134742016); // (B,4,4096)  [also dead-params sink for final lstm]
  float* part    = (float*)(ws + 143130624); // (128,32,512) = [b][ks][n]
  float* whhT    = (float*)(ws + 151519232); // (128,512), ends 151781376
  u16*   wihb    = (u16*)  (ws + 151781376); // wih bf16 (512,4096) = 4 MB, ends 155975680
  u16*   wpack   = (u16*)  (ws + 201326592); // (9,2,64,32) bf16
  float* Hbuf0   = (float*)(ws + 201400320);
  float* cbuf0   = (float*)(ws + 201465856);
  float* stats   = (float*)(ws + 201531392); // 4 x 128 f32: [0]=conv1 s0, [1]=st2 test, [2]=conv1 s1, [3]=st2 support
  if (ws_size < 201533440ull) return;

  hipMemsetAsync(Hbuf0, 0, 65536+65536+2048, stream);   // Hbuf0, cbuf0, stats contiguous
  wpack_kernel<<<144,256,0,stream>>>(w2, wpack);

  for (int s=0; s<2; s++){
    int ch = (s==0)?1:0;                   // s=0: TEST (channel 1), s=1: SUPPORT (channel 0)
    u16* dst = (s==0)? imgT : imgS;
    conv1_nhwc_kernel<<<dim3(16,128),256,0,stream>>>(imgp, ch, w1, tmp);
    stats_nhwc_kernel<<<512,256,0,stream>>>(tmp, stats + 128*(2*s));
    // conv2 (R11-proven 8-row tile): BN1 fused on input; output stays RAW
    conv2_mfma_kernel<<<dim3(32,128),256,0,stream>>>(tmp, wpack, dst,
        stats + 128*(2*s), g1, be1);
  }
  // stats2 on raw conv2 bf16 outputs, both images in one dispatch
  stats_pair_kernel<<<1024,256,0,stream>>>(imgT, imgS, stats + 128, stats + 384);

  // post-conv prologue (tmp overlay now free): whh transpose + wih bf16 pack
  transpose_whh_kernel<<<256,256,0,stream>>>(whh, whhT);
  wihpack_kernel<<<8192,256,0,stream>>>(wih, wihb);

  // turn loop: 2 dispatches per turn; BN2+res+relu applied inside glimpse.
  for (int t=0; t<16; t++){
    int sup = t&1;
    const u16* im = sup? imgS : imgT;
    const float* st2 = sup? (stats+384) : (stats+128);
    int ch = sup? 0 : 1;
    const float* Hin = sup? Hbuf0 : Hbuf1;
    const float* Cin = sup? cbuf0 : cbuf1;
    float* Hout = sup? Hbuf1 : Hbuf0;
    float* Cout = sup? cbuf1 : cbuf0;
    glimpse_lstm_kernel<<<dim3(4,128),512,0,stream>>>(
        im, part, whhT, bih, bhh, gw, gb, Hin, Cin, Hout, Cout, part_gl,
        st2, g2, be2, imgp, ch, t);
    gemm_ih_kernel<<<dim3(4,32),256,0,stream>>>(part_gl, wihb, part);
  }
  // H(15) in Hbuf1; final LSTM consumes part(15) -> H(16) in-place in Hbuf1.
  lstm_update_kernel<<<128,256,0,stream>>>(Hbuf1, cbuf1, part, whhT, bih, bhh, gw, gb,
                                           part_gl, part_gl + 65536 /*dead sinks*/);

  hipMemcpyAsync(d_out, Hbuf1, (size_t)16384*4, hipMemcpyDeviceToDevice, stream);
}

// Round 17
// 1292.377 us; speedup vs baseline: 1.1191x; 1.1191x over previous
//
#include <hip/hip_runtime.h>
#include <math.h>

typedef unsigned short u16;
typedef unsigned int u32;
typedef short bf16x8 __attribute__((ext_vector_type(8)));
typedef float f32x4 __attribute__((ext_vector_type(4)));

#define PI_F 3.14159265358979323846f

__device__ __forceinline__ float bf2f(u16 u){ union{u32 i; float f;} v; v.i=((u32)u)<<16; return v.f; }
__device__ __forceinline__ u16 f2bf(float f){ union{u32 i; float f;} v; v.f=f; u32 r=v.i+0x7fffu+((v.i>>16)&1u); return (u16)(r>>16); }
__device__ __forceinline__ float sigf(float x){ return 1.0f/(1.0f+expf(-x)); }

// ---------------- pack conv2 weights to bf16 fragment order: wpack[tap][chunk][oc][k=q*8+j] ----------------
__global__ __launch_bounds__(256) void wpack_kernel(const float* __restrict__ w2, u16* __restrict__ wpack)
{
  int e = blockIdx.x*256 + threadIdx.x;   // 36864 = 9*2*64*32
  if (e >= 36864) return;
  int k  = e & 31;
  int oc = (e>>5) & 63;
  int tc = e>>11;            // 0..17
  int tap = tc>>1, c = tc&1;
  int ic = c*32 + k;
  wpack[e] = f2bf(w2[(size_t)(oc*64 + ic)*9 + tap]);
}

// ---------------- pack wih (512x4096 f32) -> bf16 row-major ----------------
__global__ __launch_bounds__(256) void wihpack_kernel(const float* __restrict__ wih, u16* __restrict__ wihb)
{
  int e = blockIdx.x*256 + threadIdx.x;   // 2097152 total
  wihb[e] = f2bf(wih[e]);
}

// ---------------- conv1: img (B,2,64,64)[ch] f32 -> bf16 NHWC (B,64,64,64ch) (bias dropped: cancels in BN) ----------------
__global__ __launch_bounds__(256) void conv1_nhwc_kernel(
    const float* __restrict__ imgp, int ch,
    const float* __restrict__ w1, u16* __restrict__ out)
{
  int b = blockIdx.y, tile = blockIdx.x;
  int ty0 = (tile>>2)<<4, tx0 = (tile&3)<<4;
  int tid = threadIdx.x;
  __shared__ float patch[18*18];
  __shared__ float wsm[576];
  const float* ib = imgp + (((size_t)b*2 + ch)<<12);
  for (int e=tid; e<324; e+=256){
    int py = e/18, px = e - py*18;
    int gy = ty0+py-1, gx = tx0+px-1;
    float v = 0.f;
    if (gy>=0 && gy<64 && gx>=0 && gx<64) v = ib[(gy<<6)+gx];
    patch[e] = v;
  }
  for (int e=tid; e<576; e+=256) wsm[e] = w1[e];
  __syncthreads();
  int ty = tid>>4, tx = tid&15;
  float p[9];
  #pragma unroll
  for (int ky=0;ky<3;ky++)
    #pragma unroll
    for (int kx=0;kx<3;kx++) p[ky*3+kx] = patch[(ty+ky)*18 + tx+kx];
  u16* ob = out + ((((size_t)b<<12) + ((size_t)(ty0+ty)<<6) + (size_t)(tx0+tx))<<6);
  #pragma unroll
  for (int ocq=0; ocq<8; ocq++){
    u32 w4[4];
    #pragma unroll
    for (int pair=0; pair<4; pair++){
      float a0=0.f, a1=0.f;
      int oc0 = ocq*8 + pair*2;
      #pragma unroll
      for (int k=0;k<9;k++){ a0 += wsm[oc0*9+k]*p[k]; a1 += wsm[(oc0+1)*9+k]*p[k]; }
      w4[pair] = (u32)f2bf(a0) | ((u32)f2bf(a1)<<16);
    }
    ((uint4*)ob)[ocq] = make_uint4(w4[0],w4[1],w4[2],w4[3]);
  }
}

// ---------------- per-channel sum/sumsq over NHWC bf16 buf -> st[0..63]=sum, st[64..127]=sumsq ----------------
__device__ __forceinline__ void stats_body(const u16* __restrict__ buf, float* __restrict__ st, int blk, int tid)
{
  int c8 = (tid&7)*8;
  int pg = tid>>3;                 // 0..31
  size_t p0 = (size_t)blk*1024 + pg;
  float s[8], s2[8];
  #pragma unroll
  for (int k=0;k<8;k++){ s[k]=0.f; s2[k]=0.f; }
  for (int it=0; it<32; it++){
    size_t p = p0 + (size_t)it*32;
    uint4 v = *(const uint4*)(buf + (p<<6) + c8);
    u32 rw[4] = {v.x,v.y,v.z,v.w};
    #pragma unroll
    for (int d=0; d<4; d++){
      float f0 = bf2f((u16)(rw[d]&0xffff));
      float f1 = bf2f((u16)(rw[d]>>16));
      s[d*2]   += f0; s2[d*2]   += f0*f0;
      s[d*2+1] += f1; s2[d*2+1] += f1*f1;
    }
  }
  #pragma unroll
  for (int off=32; off>=8; off>>=1){
    #pragma unroll
    for (int k=0;k<8;k++){ s[k] += __shfl_down(s[k], off, 64); s2[k] += __shfl_down(s2[k], off, 64); }
  }
  __shared__ float sm[128];
  if (tid<128) sm[tid]=0.f;
  __syncthreads();
  if ((tid&63) < 8){
    int cb = tid&7;
    #pragma unroll
    for (int k=0;k<8;k++){
      atomicAdd(&sm[cb*8+k], s[k]);
      atomicAdd(&sm[64+cb*8+k], s2[k]);
    }
  }
  __syncthreads();
  if (tid<128) atomicAdd(&st[tid], sm[tid]);
}

__global__ __launch_bounds__(256) void stats_nhwc_kernel(const u16* __restrict__ buf, float* __restrict__ st)
{
  stats_body(buf, st, blockIdx.x, threadIdx.x);
}

__global__ __launch_bounds__(256) void stats_pair_kernel(
    const u16* __restrict__ A, const u16* __restrict__ B,
    float* __restrict__ stA, float* __restrict__ stB)
{
  const u16* buf = (blockIdx.x < 512)? A : B;
  float* st = (blockIdx.x < 512)? stA : stB;
  stats_body(buf, st, blockIdx.x & 511, threadIdx.x);
}

// ---------------- conv2 MFMA (R11-proven, 104 µs): 8-row x 16-col tiles, fused BN1+ReLU staging ----------------
__global__ __launch_bounds__(256) void conv2_mfma_kernel(
    const u16* __restrict__ in, const u16* __restrict__ wpack, u16* __restrict__ out,
    const float* __restrict__ st, const float* __restrict__ gam, const float* __restrict__ bet)
{
  int b = blockIdx.y, tile = blockIdx.x;     // 32 tiles: 8 y-tiles x 4 x-tiles
  int y0 = (tile>>2)*8, x0 = (tile&3)*16;
  int tid = threadIdx.x;
  int w = tid>>6, lane = tid&63;
  int m = lane&15, q = lane>>4;

  __shared__ __align__(16) u16 patch[11520];  // [py10][cq8][px18][j8]
  __shared__ float scs[64], shs[64];

  if (tid < 64){
    const float invN = 1.0f/524288.0f;
    float mean = st[tid]*invN;
    float var  = st[64+tid]*invN - mean*mean;
    float sc = gam[tid]*rsqrtf(var+1e-5f);
    scs[tid] = sc;
    shs[tid] = bet[tid] - mean*sc;
  }
  __syncthreads();

  for (int e=tid; e<1440; e+=256){
    int py = e/144; int rem = e - py*144;
    int px = rem>>3, cq = rem&7;
    int y = y0-1+py, x = x0-1+px;
    uint4 v = make_uint4(0,0,0,0);
    if (y>=0 && y<64 && x>=0 && x<64){
      uint4 raw = *(const uint4*)(in + ((((size_t)b<<12) + ((size_t)y<<6) + (size_t)x)<<6) + cq*8);
      u32 rw[4] = {raw.x, raw.y, raw.z, raw.w};
      u32 ow[4];
      #pragma unroll
      for (int d=0; d<4; d++){
        u32 o = 0;
        #pragma unroll
        for (int h=0; h<2; h++){
          int c = cq*8 + d*2 + h;
          float f = bf2f((u16)((rw[d]>>(16*h))&0xffff))*scs[c] + shs[c];
          f = fmaxf(f, 0.f);
          o |= ((u32)f2bf(f)) << (16*h);
        }
        ow[d] = o;
      }
      v = make_uint4(ow[0],ow[1],ow[2],ow[3]);
    }
    *(uint4*)(patch + ((((py<<3)+cq)*18 + px)<<3)) = v;
  }
  __syncthreads();

  f32x4 acc[2][4];
  #pragma unroll
  for (int mt=0;mt<2;mt++)
    #pragma unroll
    for (int nt=0;nt<4;nt++) acc[mt][nt] = (f32x4){0.f,0.f,0.f,0.f};

  #pragma unroll
  for (int tap=0; tap<9; tap++){
    const int dy = tap/3, dx = tap%3;
    #pragma unroll
    for (int c=0; c<2; c++){
      const int kk = tap*2 + c;
      bf16x8 bw[4];
      #pragma unroll
      for (int nt=0; nt<4; nt++)
        bw[nt] = *(const bf16x8*)(wpack + (size_t)(kk*64 + nt*16 + m)*32 + q*8);
      #pragma unroll
      for (int mt=0; mt<2; mt++){
        int py = 2*w + mt + dy;
        bf16x8 av = *(const bf16x8*)(patch + ((((py<<3) + (c<<2) + q)*18 + (m+dx))<<3));
        #pragma unroll
        for (int nt=0; nt<4; nt++)
          acc[mt][nt] = __builtin_amdgcn_mfma_f32_16x16x32_bf16(av, bw[nt], acc[mt][nt], 0,0,0);
      }
    }
  }
  __syncthreads();
  // epilogue: C/D mapping col(oc)=lane&15, row(x)=q*4+reg
  u16* etile = patch;                        // reuse: 128px x 64oc bf16 = 16KB
  #pragma unroll
  for (int mt=0; mt<2; mt++){
    int lp = (2*w+mt)*16 + q*4;
    #pragma unroll
    for (int nt=0; nt<4; nt++)
      #pragma unroll
      for (int r=0; r<4; r++)
        etile[(lp+r)*64 + nt*16 + m] = f2bf(acc[mt][nt][r]);
  }
  __syncthreads();
  int lp = tid>>1, half = tid&1;
  int y = y0 + (lp>>4), x = x0 + (lp&15);
  uint4* gdst = (uint4*)(out + ((((size_t)b<<12) + ((size_t)y<<6) + (size_t)x)<<6) + half*32);
  const uint4* lsrc = (const uint4*)(etile + lp*64 + half*32);
  gdst[0] = lsrc[0];
  gdst[1] = lsrc[1];
  gdst[2] = lsrc[2];
  gdst[3] = lsrc[3];
}

// ---------------- glimpser params -> global (final lstm only; dead sinks) ----------------
__device__ __forceinline__ void compute_params_lane(
    int b, int lane, float h0, float h1,
    const float* __restrict__ gw, const float* __restrict__ gb,
    float* __restrict__ FhT, float* __restrict__ Fw)
{
  float gpv[3];
  #pragma unroll
  for (int k=0;k<3;k++){
    float p = h0*gw[k*128+lane] + h1*gw[k*128+64+lane];
    #pragma unroll
    for (int off=32; off>0; off>>=1) p += __shfl_down(p, off, 64);
    float tot = __shfl(p, 0, 64);
    gpv[k] = tanhf(tot + gb[k]);
  }
  float ad = fabsf(gpv[2]);
  float delta = 8.0f*(1.0f-ad);
  float gamma = expf(1.0f-2.0f*ad);
  float inv_pg = 1.0f/(PI_F*gamma);
  float fi = (float)lane;
  float ctr = 31.5f*(gpv[0]+1.0f);
  float fh[8];
  #pragma unroll
  for (int g=0; g<8; g++){
    float mu = ctr + delta*((float)g - 3.5f);
    float u = (fi - mu)/gamma;
    float f = inv_pg/(1.0f+u*u);
    float s = f;
    #pragma unroll
    for (int off=32; off>0; off>>=1) s += __shfl_down(s, off, 64);
    s = __shfl(s, 0, 64);
    fh[g] = f/(s + 1e-4f);
  }
  float4* o = (float4*)(FhT + (((size_t)b<<6) + lane)*8);
  o[0] = make_float4(fh[0],fh[1],fh[2],fh[3]);
  o[1] = make_float4(fh[4],fh[5],fh[6],fh[7]);
  ctr = 31.5f*(gpv[1]+1.0f);
  #pragma unroll
  for (int wv=0; wv<8; wv++){
    float mu = ctr + delta*((float)wv - 3.5f);
    float u = (fi - mu)/gamma;
    float f = inv_pg/(1.0f+u*u);
    float s = f;
    #pragma unroll
    for (int off=32; off>0; off>>=1) s += __shfl_down(s, off, 64);
    s = __shfl(s, 0, 64);
    Fw[(((size_t)b<<3)+wv)*64 + lane] = f/(s + 1e-4f);
  }
}

// ---------------- glimpser params -> LDS, 4-wave parallel (gpv redundant per wave; g/wv split 2-per-wave) ----------------
__device__ __forceinline__ void compute_params_lds_all(
    int tid, int jc, const float* __restrict__ hnew,
    const float* __restrict__ gw, const float* __restrict__ gb,
    float* __restrict__ fh_lds, float* __restrict__ fw_lds)
{
  int lane = tid & 63, w = tid >> 6;
  if (w >= 4) return;                    // waves 4..7 proceed to barrier
  float h0 = hnew[lane], h1 = hnew[64+lane];
  float gpv[3];
  #pragma unroll
  for (int k=0;k<3;k++){
    float p = h0*gw[k*128+lane] + h1*gw[k*128+64+lane];
    #pragma unroll
    for (int off=32; off>0; off>>=1) p += __shfl_down(p, off, 64);
    float tot = __shfl(p, 0, 64);
    gpv[k] = tanhf(tot + gb[k]);
  }
  float ad = fabsf(gpv[2]);
  float delta = 8.0f*(1.0f-ad);
  float gamma = expf(1.0f-2.0f*ad);
  float inv_pg = 1.0f/(PI_F*gamma);
  float fi = (float)lane;
  float ctrH = 31.5f*(gpv[0]+1.0f);
  #pragma unroll
  for (int gg=0; gg<2; gg++){
    int g = w*2 + gg;
    float mu = ctrH + delta*((float)g - 3.5f);
    float u = (fi - mu)/gamma;
    float f = inv_pg/(1.0f+u*u);
    float s = f;
    #pragma unroll
    for (int off=32; off>0; off>>=1) s += __shfl_down(s, off, 64);
    s = __shfl(s, 0, 64);
    fh_lds[lane*8+g] = f/(s + 1e-4f);      // [i=lane][g]
  }
  float ctrW = 31.5f*(gpv[1]+1.0f);
  #pragma unroll
  for (int gg=0; gg<2; gg++){
    int wv = w*2 + gg;
    float mu = ctrW + delta*((float)wv - 3.5f);
    float u = (fi - mu)/gamma;
    float f = inv_pg/(1.0f+u*u);
    float s = f;
    #pragma unroll
    for (int off=32; off>0; off>>=1) s += __shfl_down(s, off, 64);
    s = __shfl(s, 0, 64);
    int jl = lane - jc*16;
    if (jl >= 0 && jl < 16) fw_lds[jl*8+wv] = f/(s + 1e-4f);   // [jl][w]
  }
}

// ---------------- glimpse + folded LSTM/params (R14-proven): 512 threads, 4-way row split, single t_lds ----------------
__global__ __launch_bounds__(512,4) void glimpse_lstm_kernel(
    const u16* __restrict__ img, const float* __restrict__ part,
    const float* __restrict__ whhT,
    const float* __restrict__ bih, const float* __restrict__ bhh,
    const float* __restrict__ gw, const float* __restrict__ gb,
    const float* __restrict__ Hx_in, const float* __restrict__ Cx_in,
    float* __restrict__ Hx_out, float* __restrict__ Cx_out,
    float* __restrict__ part_gl,
    const float* __restrict__ st2, const float* __restrict__ gam2,
    const float* __restrict__ bet2, const float* __restrict__ imgp,
    int ch, int t)
{
  int jc = blockIdx.x, b = blockIdx.y;
  int tid = threadIdx.x;
  __shared__ float hs[128];
  __shared__ float hnew[128];
  __shared__ float gsm[512];
  __shared__ float scs[64], shs[64];
  __shared__ __align__(16) float fh_lds[512];     // [i][g]
  __shared__ __align__(16) float fw_lds[128];     // [jl][w]
  __shared__ __align__(16) float t_lds[8*16*64];  // [g][j][c]

  // ---- BN2 coefficients ----
  if (tid < 64){
    const float invN = 1.0f/524288.0f;
    float mean = st2[tid]*invN;
    float var  = st2[64+tid]*invN - mean*mean;
    float sc = gam2[tid]*rsqrtf(var+1e-5f);
    scs[tid] = sc;
    shs[tid] = bet2[tid] - mean*sc;
  }

  // ---- folded LSTM (512 threads: n = tid covers all 512 gates directly) ----
  if (t > 0){
    if (tid < 128) hs[tid] = Hx_in[b*128+tid];
    __syncthreads();
    {
      int n = tid;
      float acc = bih[n] + bhh[n];
      const float* pp = part + (size_t)b*16384 + n;
      #pragma unroll 8
      for (int ks=0; ks<32; ks++) acc += pp[ks*512];
      const float* wp = whhT + n;
      #pragma unroll 8
      for (int k=0;k<128;k++) acc += hs[k]*wp[(size_t)k*512];
      gsm[n] = acc;
    }
    __syncthreads();
    if (tid < 128){
      float cx = Cx_in[b*128+tid];
      float cn = sigf(gsm[128+tid])*cx + sigf(gsm[tid])*tanhf(gsm[256+tid]);
      float hn = sigf(gsm[384+tid])*tanhf(cn);
      hnew[tid] = hn;
      if (jc == 0){ Cx_out[b*128+tid] = cn; Hx_out[b*128+tid] = hn; }
    }
  } else {
    if (tid < 128) hnew[tid] = 0.f;
  }
  __syncthreads();

  // ---- params in-LDS (4 waves in parallel) ----
  compute_params_lds_all(tid, jc, hnew, gw, gb, fh_lds, fw_lds);
  __syncthreads();

  // ---- glimpse phase 1: uint4 loads + BN2/res/relu, 4-way row split (16 rows each) ----
  int ih = tid>>7, j = (tid>>3)&15, cg = tid&7;
  float scq[8], shq[8];
  #pragma unroll
  for (int k=0;k<8;k++){ scq[k] = scs[cg*8+k]; shq[k] = shs[cg*8+k]; }
  f32x4 accA[8], accB[8];
  #pragma unroll
  for (int g=0;g<8;g++){ accA[g]=(f32x4){0.f,0.f,0.f,0.f}; accB[g]=(f32x4){0.f,0.f,0.f,0.f}; }
  const u16* ib = img + ((((size_t)b<<12) + ((size_t)(ih*16)<<6) + (size_t)(jc*16+j))<<6) + cg*8;
  const float* rp = imgp + (((size_t)(b*2+ch))<<12) + ((size_t)(ih*16)<<6) + (jc*16+j);
  #pragma unroll 8
  for (int ii=0; ii<16; ii++){
    uint4 vv = *(const uint4*)(ib + ((size_t)ii<<12));
    float res = rp[ii<<6];
    float x0=fmaxf(bf2f((u16)(vv.x&0xffff))*scq[0]+shq[0]+res, 0.f);
    float x1=fmaxf(bf2f((u16)(vv.x>>16))   *scq[1]+shq[1]+res, 0.f);
    float x2=fmaxf(bf2f((u16)(vv.y&0xffff))*scq[2]+shq[2]+res, 0.f);
    float x3=fmaxf(bf2f((u16)(vv.y>>16))   *scq[3]+shq[3]+res, 0.f);
    float x4=fmaxf(bf2f((u16)(vv.z&0xffff))*scq[4]+shq[4]+res, 0.f);
    float x5=fmaxf(bf2f((u16)(vv.z>>16))   *scq[5]+shq[5]+res, 0.f);
    float x6=fmaxf(bf2f((u16)(vv.w&0xffff))*scq[6]+shq[6]+res, 0.f);
    float x7=fmaxf(bf2f((u16)(vv.w>>16))   *scq[7]+shq[7]+res, 0.f);
    int i = ih*16+ii;
    f32x4 fa = *(const f32x4*)&fh_lds[i*8];
    f32x4 fb = *(const f32x4*)&fh_lds[i*8+4];
    #pragma unroll
    for (int g=0;g<4;g++){
      accA[g][0]+=fa[g]*x0; accA[g][1]+=fa[g]*x1; accA[g][2]+=fa[g]*x2; accA[g][3]+=fa[g]*x3;
      accB[g][0]+=fa[g]*x4; accB[g][1]+=fa[g]*x5; accB[g][2]+=fa[g]*x6; accB[g][3]+=fa[g]*x7;
      accA[g+4][0]+=fb[g]*x0; accA[g+4][1]+=fb[g]*x1; accA[g+4][2]+=fb[g]*x2; accA[g+4][3]+=fb[g]*x3;
      accB[g+4][0]+=fb[g]*x4; accB[g+4][1]+=fb[g]*x5; accB[g+4][2]+=fb[g]*x6; accB[g+4][3]+=fb[g]*x7;
    }
  }
  // 4-step sequential combine into t_lds
  if (ih==0){
    #pragma unroll
    for (int g=0;g<8;g++){
      *(f32x4*)&t_lds[(g*16+j)*64 + cg*8]     = accA[g];
      *(f32x4*)&t_lds[(g*16+j)*64 + cg*8 + 4] = accB[g];
    }
  }
  __syncthreads();
  if (ih==1){
    #pragma unroll
    for (int g=0;g<8;g++){
      f32x4* p0 = (f32x4*)&t_lds[(g*16+j)*64 + cg*8];
      p0[0] = p0[0] + accA[g];
      p0[1] = p0[1] + accB[g];
    }
  }
  __syncthreads();
  if (ih==2){
    #pragma unroll
    for (int g=0;g<8;g++){
      f32x4* p0 = (f32x4*)&t_lds[(g*16+j)*64 + cg*8];
      p0[0] = p0[0] + accA[g];
      p0[1] = p0[1] + accB[g];
    }
  }
  __syncthreads();
  if (ih==3){
    #pragma unroll
    for (int g=0;g<8;g++){
      f32x4* p0 = (f32x4*)&t_lds[(g*16+j)*64 + cg*8];
      p0[0] = p0[0] + accA[g];
      p0[1] = p0[1] + accB[g];
    }
  }
  __syncthreads();

  // ---- glimpse phase 2: j-contraction (512 threads: 8 g-groups x 64 c) ----
  {
    int c = tid&63, s = tid>>6;        // s = g (0..7)
    float acc2[8];
    #pragma unroll
    for (int wv=0;wv<8;wv++) acc2[wv]=0.f;
    #pragma unroll
    for (int jl=0; jl<16; jl++){
      float tv = t_lds[(((s<<4)+jl)<<6) + c];
      f32x4 w0 = *(const f32x4*)&fw_lds[jl*8];
      f32x4 w1 = *(const f32x4*)&fw_lds[jl*8+4];
      acc2[0]+=tv*w0[0]; acc2[1]+=tv*w0[1]; acc2[2]+=tv*w0[2]; acc2[3]+=tv*w0[3];
      acc2[4]+=tv*w1[0]; acc2[5]+=tv*w1[1]; acc2[6]+=tv*w1[2]; acc2[7]+=tv*w1[3];
    }
    float* dst = part_gl + (((size_t)(b*4+jc))<<12) + c*64 + s*8;
    *(f32x4*)(dst+0) = (f32x4){acc2[0],acc2[1],acc2[2],acc2[3]};
    *(f32x4*)(dst+4) = (f32x4){acc2[4],acc2[5],acc2[6],acc2[7]};
  }
}

// ---------------- gates GEMM v3 (R14-proven): MFMA bf16. grid (4 n-tiles x 32 kb), 256 thr ----------------
__global__ __launch_bounds__(256) void gemm_ih_kernel(
    const float* __restrict__ part_gl, const u16* __restrict__ wihb, float* __restrict__ part)
{
  int n0 = blockIdx.x*128;
  int kb = blockIdx.y;
  int k0 = kb*128;
  __shared__ __align__(16) u16 AsmB[128*32];   // [m][k] bf16, 8 KB
  __shared__ __align__(16) u16 BsmB[128*32];   // [n][k] bf16, 8 KB
  int tid = threadIdx.x;
  int w = tid>>6, lane = tid&63;
  int m = lane&15, q = lane>>4;

  f32x4 acc[2][8];
  #pragma unroll
  for (int mf=0;mf<2;mf++)
    #pragma unroll
    for (int nf=0;nf<8;nf++) acc[mf][nf] = (f32x4){0.f,0.f,0.f,0.f};

  for (int ks=0; ks<4; ks++){
    int kbase = k0 + ks*32;
    // stage A: thread t -> row (t&127), k-half (t>>7)*16
    {
      int mr = tid & 127, half = tid >> 7;
      const float* pg = part_gl + ((size_t)mr<<14) + kbase + half*16;
      u16 tmpv[16];
      #pragma unroll
      for (int kq=0; kq<4; kq++){
        float4 a0 = *(const float4*)(pg + kq*4);
        float4 a1 = *(const float4*)(pg + 4096 + kq*4);
        float4 a2 = *(const float4*)(pg + 8192 + kq*4);
        float4 a3 = *(const float4*)(pg + 12288 + kq*4);
        tmpv[kq*4+0] = f2bf(a0.x+a1.x+a2.x+a3.x);
        tmpv[kq*4+1] = f2bf(a0.y+a1.y+a2.y+a3.y);
        tmpv[kq*4+2] = f2bf(a0.z+a1.z+a2.z+a3.z);
        tmpv[kq*4+3] = f2bf(a0.w+a1.w+a2.w+a3.w);
      }
      *(uint4*)(AsmB + mr*32 + half*16)     = *(uint4*)&tmpv[0];
      *(uint4*)(AsmB + mr*32 + half*16 + 8) = *(uint4*)&tmpv[8];
    }
    // stage B: thread t -> row n (t&127), k-half (t>>7)*16
    {
      int n = tid & 127, half = tid >> 7;
      const u16* wp = wihb + (size_t)(n0+n)*4096 + kbase + half*16;
      uint4 b0 = *(const uint4*)wp;
      uint4 b1 = *(const uint4*)(wp+8);
      *(uint4*)(BsmB + n*32 + half*16)     = b0;
      *(uint4*)(BsmB + n*32 + half*16 + 8) = b1;
    }
    __syncthreads();
    #pragma unroll
    for (int mf=0; mf<2; mf++){
      bf16x8 av = *(const bf16x8*)(AsmB + ((w*2+mf)*16 + m)*32 + q*8);
      #pragma unroll
      for (int nf=0; nf<8; nf++){
        bf16x8 bw = *(const bf16x8*)(BsmB + (nf*16 + m)*32 + q*8);
        acc[mf][nf] = __builtin_amdgcn_mfma_f32_16x16x32_bf16(av, bw, acc[mf][nf], 0,0,0);
      }
    }
    __syncthreads();
  }
  // store: row M = (w*2+mf)*16 + q*4 + r (= batch b), col N = nf*16 + m
  #pragma unroll
  for (int mf=0; mf<2; mf++){
    #pragma unroll
    for (int r=0; r<4; r++){
      int mrow = (w*2+mf)*16 + q*4 + r;
      float* pp = part + (size_t)mrow*16384 + kb*512 + n0;
      #pragma unroll
      for (int nf=0; nf<8; nf++)
        pp[nf*16 + m] = acc[mf][nf][r];
    }
  }
}

// ---------------- final LSTM update (produces H(16)); part layout [b][ks][n] ----------------
__global__ __launch_bounds__(256) void lstm_update_kernel(
    float* __restrict__ Hx, float* __restrict__ Cx,
    const float* __restrict__ part, const float* __restrict__ whhT,
    const float* __restrict__ b_ih, const float* __restrict__ b_hh,
    const float* __restrict__ gw, const float* __restrict__ gb,
    float* __restrict__ FhT, float* __restrict__ Fw)
{
  int b = blockIdx.x;
  int tid = threadIdx.x;
  int hid = tid & 127, half = tid >> 7;
  __shared__ float hs[128];
  __shared__ float hs2[128];
  __shared__ float gp[1024];     // [half][qd][hid]
  if (tid < 128) hs[tid] = Hx[b*128+tid];
  __syncthreads();
  #pragma unroll
  for (int qd=0; qd<4; qd++){
    int n = qd*128 + hid;
    float acc = half ? 0.f : (b_ih[n] + b_hh[n]);
    const float* pp = part + (size_t)b*16384 + (size_t)(half*16)*512 + n;
    #pragma unroll
    for (int ks=0; ks<16; ks++) acc += pp[ks*512];
    const float* wp = whhT + n + (size_t)(half*64)*512;
    const float* hp = hs + half*64;
    #pragma unroll 8
    for (int k=0;k<64;k++) acc += hp[k]*wp[(size_t)k*512];
    gp[(half*4+qd)*128 + hid] = acc;
  }
  __syncthreads();
  if (tid < 128){
    float g0 = gp[  0+tid] + gp[512+  0+tid];
    float g1 = gp[128+tid] + gp[512+128+tid];
    float g2 = gp[256+tid] + gp[512+256+tid];
    float g3 = gp[384+tid] + gp[512+384+tid];
    float cx = Cx[b*128+tid];
    float cn = sigf(g1)*cx + sigf(g0)*tanhf(g2);
    float hn = sigf(g3)*tanhf(cn);
    Cx[b*128+tid] = cn;
    Hx[b*128+tid] = hn;
    hs2[tid] = hn;
  }
  __syncthreads();
  if (tid < 64)
    compute_params_lane(b, tid, hs2[tid], hs2[64+tid], gw, gb, FhT, Fw);
}

__global__ __launch_bounds__(256) void transpose_whh_kernel(
    const float* __restrict__ whh, float* __restrict__ whhT)
{
  int idx = blockIdx.x*256 + threadIdx.x; // 65536 total
  int k = idx>>9, n = idx&511;
  whhT[idx] = whh[n*128 + k];
}

extern "C" void kernel_launch(void* const* d_in, const int* in_sizes, int n_in,
                              void* d_out, int out_size, void* d_ws, size_t ws_size,
                              hipStream_t stream)
{
  const float* imgp = (const float*)d_in[0];
  const float* w1  = (const float*)d_in[1];
  // d_in[2] = conv1 bias: cancels through bn1 -> unused
  const float* g1  = (const float*)d_in[3];
  const float* be1 = (const float*)d_in[4];
  const float* w2  = (const float*)d_in[5];
  // d_in[6] = conv2 bias: cancels through bn2 -> unused
  const float* g2  = (const float*)d_in[7];
  const float* be2 = (const float*)d_in[8];
  const float* wih = (const float*)d_in[9];
  const float* whh = (const float*)d_in[10];
  const float* bih = (const float*)d_in[11];
  const float* bhh = (const float*)d_in[12];
  const float* gw  = (const float*)d_in[13];
  const float* gb  = (const float*)d_in[14];

  char* ws = (char*)d_ws;
  u16* imgT    = (u16*)(ws + 0);           // RAW conv2 out (test), NHWC bf16
  u16* imgS    = (u16*)(ws + 67108864);    // RAW conv2 out (support)
  u16* tmp     = (u16*)(ws + 134217728);   // conv1 raw output, NHWC bf16 [134217728, 201326592)
  // turn-loop scratch overlays tmp (live only after conv phase):
  float* Hbuf1   = (float*)(ws + 134217728); // ping-pong H (65536)
  float* cbuf1   = (float*)(ws + 134283264); // ping-pong C (65536)
  float* part_gl = (float*)(ws + 134742016); // (B,4,4096)  [also dead-params sink for final lstm]
  float* part    = (float*)(ws + 143130624); // (128,32,512) = [b][ks][n]
  float* whhT    = (float*)(ws + 151519232); // (128,512), ends 151781376
  u16*   wihb    = (u16*)  (ws + 151781376); // wih bf16 (512,4096) = 4 MB, ends 155975680
  u16*   wpack   = (u16*)  (ws + 201326592); // (9,2,64,32) bf16
  float* Hbuf0   = (float*)(ws + 201400320);
  float* cbuf0   = (float*)(ws + 201465856);
  float* stats   = (float*)(ws + 201531392); // 4 x 128 f32: [0]=conv1 s0, [1]=st2 test, [2]=conv1 s1, [3]=st2 support
  if (ws_size < 201533440ull) return;

  hipMemsetAsync(Hbuf0, 0, 65536+65536+2048, stream);   // Hbuf0, cbuf0, stats contiguous
  wpack_kernel<<<144,256,0,stream>>>(w2, wpack);

  for (int s=0; s<2; s++){
    int ch = (s==0)?1:0;                   // s=0: TEST (channel 1), s=1: SUPPORT (channel 0)
    u16* dst = (s==0)? imgT : imgS;
    conv1_nhwc_kernel<<<dim3(16,128),256,0,stream>>>(imgp, ch, w1, tmp);
    stats_nhwc_kernel<<<512,256,0,stream>>>(tmp, stats + 128*(2*s));
    // conv2 (R11-proven 8-row tile): BN1 fused on input; output stays RAW
    conv2_mfma_kernel<<<dim3(32,128),256,0,stream>>>(tmp, wpack, dst,
        stats + 128*(2*s), g1, be1);
  }
  // stats2 on raw conv2 bf16 outputs, both images in one dispatch
  stats_pair_kernel<<<1024,256,0,stream>>>(imgT, imgS, stats + 128, stats + 384);

  // post-conv prologue (tmp overlay now free): whh transpose + wih bf16 pack
  transpose_whh_kernel<<<256,256,0,stream>>>(whh, whhT);
  wihpack_kernel<<<8192,256,0,stream>>>(wih, wihb);

  // turn loop: 2 dispatches per turn; BN2+res+relu applied inside glimpse.
  for (int t=0; t<16; t++){
    int sup = t&1;
    const u16* im = sup? imgS : imgT;
    const float* st2 = sup? (stats+384) : (stats+128);
    int ch = sup? 0 : 1;
    const float* Hin = sup? Hbuf0 : Hbuf1;
    const float* Cin = sup? cbuf0 : cbuf1;
    float* Hout = sup? Hbuf1 : Hbuf0;
    float* Cout = sup? cbuf1 : cbuf0;
    glimpse_lstm_kernel<<<dim3(4,128),512,0,stream>>>(
        im, part, whhT, bih, bhh, gw, gb, Hin, Cin, Hout, Cout, part_gl,
        st2, g2, be2, imgp, ch, t);
    gemm_ih_kernel<<<dim3(4,32),256,0,stream>>>(part_gl, wihb, part);
  }
  // H(15) in Hbuf1; final LSTM consumes part(15) -> H(16) in-place in Hbuf1.
  lstm_update_kernel<<<128,256,0,stream>>>(Hbuf1, cbuf1, part, whhT, bih, bhh, gw, gb,
                                           part_gl, part_gl + 65536 /*dead sinks*/);

  hipMemcpyAsync(d_out, Hbuf1, (size_t)16384*4, hipMemcpyDeviceToDevice, stream);
}